// Round 13
// baseline (37.687 us; speedup 1.0000x reference)
//
#include <hip/hip_runtime.h>

typedef float f4 __attribute__((ext_vector_type(4)));
typedef float f2 __attribute__((ext_vector_type(2)));

#define PAD 68              // LDS row pitch (floats); 68%32=4 spreads banks
#define NPART 256           // gram blocks = partial count
#define PART_STRIDE 12288   // 3 * 64*64 floats per block partial

// ws layout (floats):
// [0, 1048576)        pooled [2][64][8192]  (4 MB)
// [1048576, +3145728) partials [256][3][4096]
// [4194304, +256)     bpart
// [4194816]           uint counter (K2 ticket; reset by pool block 0)

// K0: one block = one (batch,channel) 64 KB plane, read fully sequentially.
// 1024 long HBM streams instead of 32K interleaved 2KB gathers.
// NOTE: 512 planes per input (8 batches x 64 ch) -> 1024 blocks total.
__global__ __launch_bounds__(256) void pool_kernel(
    const float* __restrict__ p1, const float* __restrict__ p2,
    float* __restrict__ pooled, unsigned* __restrict__ cnt)
{
    const int t = threadIdx.x;
    if (blockIdx.x == 0 && t == 0) *cnt = 0u;   // reset K2 ticket each call
    const int blk = blockIdx.x;         // 0..1023
    const int m   = blk >> 9;           // input select
    const int bc  = blk & 511;          // plane index = b*64 + c
    const int b   = bc >> 6;            // batch 0..7
    const int c   = bc & 63;            // channel 0..63
    const float* src = (m ? p2 : p1) + (long)bc * 16384;
    float* dst = pooled + (long)m * 524288 + (long)c * 8192 + b * 1024;

    #pragma unroll
    for (int k = 0; k < 4; ++k) {
        const int o  = k * 256 + t;     // pooled element 0..1023, ascending
        const int oi = o >> 5, oj = o & 31;
        const float* s = src + oi * 512 + oj * 4;
        f4 v = *(const f4*)(s) + *(const f4*)(s + 128)
             + *(const f4*)(s + 256) + *(const f4*)(s + 384);
        dst[o] = ((v[0] + v[1]) + (v[2] + v[3])) * 0.0625f;
    }
}

// K1': stage pooled strip from cache, norm via per-wave shfl, gram (r3 tile).
__global__ __launch_bounds__(1024) void gram_kernel(
    const float* __restrict__ pooled, float* __restrict__ partials)
{
    __shared__ float la[32 * PAD];
    __shared__ float lb[32 * PAD];
    const int t  = threadIdx.x;
    const int b  = blockIdx.x >> 5;    // batch 0..7
    const int oi = blockIdx.x & 31;    // pooled row strip 0..31

    // ---- stage: 1024 f4 slots = 2 inputs x 64 ch x 8 oj-quads (16 KB)
    {
        const int oj4 = t & 7;
        const int c   = (t >> 3) & 63;
        const int m   = t >> 9;
        const f4 v = *(const f4*)&pooled[(long)m * 524288 + (long)c * 8192
                                         + b * 1024 + oi * 32 + oj4 * 4];
        float* dst = (m ? lb : la) + c;          // LDS layout [oj][c]
        dst[(oj4 * 4 + 0) * PAD] = v[0];
        dst[(oj4 * 4 + 1) * PAD] = v[1];
        dst[(oj4 * 4 + 2) * PAD] = v[2];
        dst[(oj4 * 4 + 3) * PAD] = v[3];
    }
    __syncthreads();

    // ---- norm: 16 waves x 4 rowslots; lane = channel; rescale in place
    {
        const int w = t >> 6, l = t & 63;
        #pragma unroll
        for (int j = 0; j < 4; ++j) {
            const int rs = j * 16 + w;           // rowslot 0..63
            const int m = rs >> 5, r = rs & 31;
            float* rowp = (m ? lb : la) + r * PAD;
            const float v = rowp[l];
            float ss = v * v;
            ss += __shfl_xor(ss, 1);
            ss += __shfl_xor(ss, 2);
            ss += __shfl_xor(ss, 4);
            ss += __shfl_xor(ss, 8);
            ss += __shfl_xor(ss, 16);
            ss += __shfl_xor(ss, 32);
            rowp[l] = v * (1.0f / fmaxf(sqrtf(ss), 1e-8f));
        }
    }
    __syncthreads();

    // ---- three 64x64 Grams over 32 rows; 2x2 tile per thread (r3-identical)
    const int c1 = (t >> 5) * 2;
    const int c2 = (t & 31) * 2;
    f2 aa0 = {}, aa1 = {}, ab0 = {}, ab1 = {}, bb0 = {}, bb1 = {};

    #pragma unroll 8
    for (int r = 0; r < 32; ++r) {
        const f2 a1 = *(const f2*)&la[r * PAD + c1];
        const f2 a2 = *(const f2*)&la[r * PAD + c2];
        const f2 b1 = *(const f2*)&lb[r * PAD + c1];
        const f2 b2 = *(const f2*)&lb[r * PAD + c2];
        aa0 += a2 * a1[0];  aa1 += a2 * a1[1];
        ab0 += b2 * a1[0];  ab1 += b2 * a1[1];
        bb0 += b2 * b1[0];  bb1 += b2 * b1[1];
    }

    float* P = partials + (long)blockIdx.x * PART_STRIDE;
    *(f2*)&P[0 * 4096 + (c1    ) * 64 + c2] = aa0;
    *(f2*)&P[0 * 4096 + (c1 + 1) * 64 + c2] = aa1;
    *(f2*)&P[1 * 4096 + (c1    ) * 64 + c2] = ab0;
    *(f2*)&P[1 * 4096 + (c1 + 1) * 64 + c2] = ab1;
    *(f2*)&P[2 * 4096 + (c1    ) * 64 + c2] = bb0;
    *(f2*)&P[2 * 4096 + (c1 + 1) * 64 + c2] = bb1;
}

// K2: byte-identical to round 3's (best measured): 256 blocks x 256 threads.
__global__ __launch_bounds__(256) void reduce_kernel(
    const float* __restrict__ partials, float* __restrict__ bpart,
    unsigned* __restrict__ cnt, float* __restrict__ out)
{
    __shared__ float red[3][16][17];
    __shared__ float vred[16];
    __shared__ float fr[256];
    __shared__ unsigned last_flag;
    const int t  = threadIdx.x;
    const int el = t & 15;
    const int pc = t >> 4;
    const int e  = blockIdx.x * 16 + el;

    float saa = 0.f, sab = 0.f, sbb = 0.f;
    #pragma unroll 4
    for (int i = 0; i < 16; ++i) {
        const float* P = partials + (long)(pc * 16 + i) * PART_STRIDE;
        saa += P[e];
        sab += P[4096 + e];
        sbb += P[8192 + e];
    }
    red[0][el][pc] = saa; red[1][el][pc] = sab; red[2][el][pc] = sbb;
    __syncthreads();

    if (t < 16) {
        float a = 0.f, mm = 0.f, bv = 0.f;
        #pragma unroll
        for (int p = 0; p < 16; ++p) {
            a  += red[0][t][p];
            mm += red[1][t][p];
            bv += red[2][t][p];
        }
        vred[t] = fmaf(a, a, fmaf(bv, bv, -2.0f * (mm * mm)));
    }
    __syncthreads();

    if (t == 0) {
        float s = 0.f;
        #pragma unroll
        for (int i = 0; i < 16; ++i) s += vred[i];
        __hip_atomic_store(&bpart[blockIdx.x], s, __ATOMIC_RELEASE,
                           __HIP_MEMORY_SCOPE_AGENT);
        unsigned old = __hip_atomic_fetch_add(cnt, 1u, __ATOMIC_ACQ_REL,
                                              __HIP_MEMORY_SCOPE_AGENT);
        last_flag = (old == NPART - 1) ? 1u : 0u;
    }
    __syncthreads();

    if (last_flag) {   // block-uniform
        fr[t] = __hip_atomic_load(&bpart[t], __ATOMIC_ACQUIRE,
                                  __HIP_MEMORY_SCOPE_AGENT);
        __syncthreads();
        for (int s2 = 128; s2 > 0; s2 >>= 1) {
            if (t < s2) fr[t] += fr[t + s2];
            __syncthreads();
        }
        if (t == 0) out[0] = fr[0] * (1.0f / 67108864.0f);  // / 8192^2
    }
}

extern "C" void kernel_launch(void* const* d_in, const int* in_sizes, int n_in,
                              void* d_out, int out_size, void* d_ws, size_t ws_size,
                              hipStream_t stream)
{
    const float* p1 = (const float*)d_in[0];
    const float* p2 = (const float*)d_in[1];
    float* ws       = (float*)d_ws;
    float* pooled   = ws;                                  // 2*64*8192
    float* partials = ws + 1048576;                        // 256*12288
    float* bpart    = ws + 4194304;                        // 256
    unsigned* cnt   = (unsigned*)(ws + 4194816);           // 1

    pool_kernel  <<<1024, 256, 0, stream>>>(p1, p2, pooled, cnt);
    gram_kernel  <<<NPART, 1024, 0, stream>>>(pooled, partials);
    reduce_kernel<<<NPART, 256, 0, stream>>>(partials, bpart, cnt, (float*)d_out);
}

// Round 14
// 37.421 us; speedup vs baseline: 1.0071x; 1.0071x over previous
//
#include <hip/hip_runtime.h>

typedef float f4 __attribute__((ext_vector_type(4)));
typedef float f2 __attribute__((ext_vector_type(2)));

#define PAD 68              // LDS row pitch (floats); 68%32=4 spreads banks
#define NPART 256           // gram blocks = partial count
#define PART_STRIDE 12288   // 3 * 64*64 floats per block partial

// ws layout (floats):
// [0, 3145728)      partials [256][3][4096]
// [3145728, +256)   bpart (K2)
// [3146240]         uint counter (K2 ticket; reset by K1 block 0)

// Barrier that does NOT drain outstanding global loads (prefetch survives):
// LDS ordering via lgkmcnt(0), then raw s_barrier; sched_barrier pins code
// motion so later ds ops can't hoist above the barrier.
__device__ __forceinline__ void lds_barrier() {
    asm volatile("s_waitcnt lgkmcnt(0)" ::: "memory");
    __builtin_amdgcn_s_barrier();
    __builtin_amdgcn_sched_barrier(0);
}

__global__ __launch_bounds__(1024) void fused_gram_kernel(
    const float* __restrict__ p1, const float* __restrict__ p2,
    float* __restrict__ partials, unsigned* __restrict__ cnt)
{
    __shared__ float la[2][8 * PAD];   // double-buffered 8-row tiles, input A
    __shared__ float lb[2][8 * PAD];   // and input B
    const int t  = threadIdx.x;
    const int b  = blockIdx.x >> 5;    // batch 0..7
    const int oi = blockIdx.x & 31;    // pooled row strip 0..31

    if (blockIdx.x == 0 && t == 0) *cnt = 0u;   // reset K2 ticket each call

    // --- per-thread pool slot: one pooled value per sub-strip ---
    const int m   = t >> 9;            // input select 0/1
    const int c   = (t >> 3) & 63;     // channel
    const int oj8 = t & 7;             // row within sub (8 lanes = 128B seg)
    const float* src = m ? p2 : p1;
    const long base = (long)((b * 64 + c) * 128 + oi * 4) * 128 + oj8 * 4;
    float* dst0 = m ? lb[0] : la[0];
    float* dst1 = m ? lb[1] : la[1];

    // --- norm-wave assignment: wave w owns row (nm, nr), lane = channel ---
    const int l  = t & 63;
    const int w  = t >> 6;
    const int nm = w >> 3, nr = w & 7;

    // --- gram 2x2 tile (r3-identical) ---
    const int c1 = (t >> 5) * 2;
    const int c2 = (t & 31) * 2;
    f2 aa0 = {}, aa1 = {}, ab0 = {}, ab1 = {}, bb0 = {}, bb1 = {};

    auto issue = [&](int q, f4& R0, f4& R1, f4& R2, f4& R3) {
        const float* s = src + base + q * 32;   // sub q: oj = q*8 + oj8
        R0 = *(const f4*)(s);
        R1 = *(const f4*)(s + 128);
        R2 = *(const f4*)(s + 256);
        R3 = *(const f4*)(s + 384);
    };
    auto pool = [&](const f4& R0, const f4& R1, const f4& R2, const f4& R3,
                    float* dst) {
        const f4 v = (R0 + R1) + (R2 + R3);
        dst[oj8 * PAD + c] = ((v[0] + v[1]) + (v[2] + v[3])) * 0.0625f;
    };
    auto normphase = [&](int bi) {     // 16 waves: reduce + rescale in place
        float* rowp = (nm ? lb[bi] : la[bi]) + nr * PAD;
        const float v = rowp[l];
        float ss = v * v;
        ss += __shfl_xor(ss, 1);
        ss += __shfl_xor(ss, 2);
        ss += __shfl_xor(ss, 4);
        ss += __shfl_xor(ss, 8);
        ss += __shfl_xor(ss, 16);
        ss += __shfl_xor(ss, 32);
        rowp[l] = v * (1.0f / fmaxf(sqrtf(ss), 1e-8f));
    };
    auto gram = [&](int bi) {
        #pragma unroll
        for (int r = 0; r < 8; ++r) {
            const f2 a1 = *(const f2*)&la[bi][r * PAD + c1];
            const f2 a2 = *(const f2*)&la[bi][r * PAD + c2];
            const f2 b1 = *(const f2*)&lb[bi][r * PAD + c1];
            const f2 b2 = *(const f2*)&lb[bi][r * PAD + c2];
            aa0 += a2 * a1[0];  aa1 += a2 * a1[1];
            ab0 += b2 * a1[0];  ab1 += b2 * a1[1];
            bb0 += b2 * b1[0];  bb1 += b2 * b1[1];
        }
    };

    // ---- software pipeline, depth 4: ALL 16 loads issued before the first
    // barrier; lds_barrier never waits vmcnt, so the HBM stream stays fully
    // primed from first instruction to last pool. Buffer alternation gives
    // >=2 barriers between gram(buf) and the next pool-write of that buf.
    f4 A0, A1, A2, A3, B0, B1, B2, B3;
    f4 C0, C1, C2, C3, D0, D1, D2, D3;
    issue(0, A0, A1, A2, A3);
    issue(1, B0, B1, B2, B3);
    issue(2, C0, C1, C2, C3);
    issue(3, D0, D1, D2, D3);

    pool(A0, A1, A2, A3, dst0);  lds_barrier();
    normphase(0);                lds_barrier();
    gram(0);

    pool(B0, B1, B2, B3, dst1);  lds_barrier();
    normphase(1);                lds_barrier();
    gram(1);

    pool(C0, C1, C2, C3, dst0);  lds_barrier();
    normphase(0);                lds_barrier();
    gram(0);

    pool(D0, D1, D2, D3, dst1);  lds_barrier();
    normphase(1);                lds_barrier();
    gram(1);

    // ---- partial store: byte-identical layout to round 3 ----
    float* P = partials + (long)blockIdx.x * PART_STRIDE;
    *(f2*)&P[0 * 4096 + (c1    ) * 64 + c2] = aa0;
    *(f2*)&P[0 * 4096 + (c1 + 1) * 64 + c2] = aa1;
    *(f2*)&P[1 * 4096 + (c1    ) * 64 + c2] = ab0;
    *(f2*)&P[1 * 4096 + (c1 + 1) * 64 + c2] = ab1;
    *(f2*)&P[2 * 4096 + (c1    ) * 64 + c2] = bb0;
    *(f2*)&P[2 * 4096 + (c1 + 1) * 64 + c2] = bb1;
}

// K2: byte-identical to round 3's (best measured): 256 blocks x 256 threads.
__global__ __launch_bounds__(256) void reduce_kernel(
    const float* __restrict__ partials, float* __restrict__ bpart,
    unsigned* __restrict__ cnt, float* __restrict__ out)
{
    __shared__ float red[3][16][17];
    __shared__ float vred[16];
    __shared__ float fr[256];
    __shared__ unsigned last_flag;
    const int t  = threadIdx.x;
    const int el = t & 15;
    const int pc = t >> 4;
    const int e  = blockIdx.x * 16 + el;

    float saa = 0.f, sab = 0.f, sbb = 0.f;
    #pragma unroll 4
    for (int i = 0; i < 16; ++i) {
        const float* P = partials + (long)(pc * 16 + i) * PART_STRIDE;
        saa += P[e];
        sab += P[4096 + e];
        sbb += P[8192 + e];
    }
    red[0][el][pc] = saa; red[1][el][pc] = sab; red[2][el][pc] = sbb;
    __syncthreads();

    if (t < 16) {
        float a = 0.f, mm = 0.f, bv = 0.f;
        #pragma unroll
        for (int p = 0; p < 16; ++p) {
            a  += red[0][t][p];
            mm += red[1][t][p];
            bv += red[2][t][p];
        }
        vred[t] = fmaf(a, a, fmaf(bv, bv, -2.0f * (mm * mm)));
    }
    __syncthreads();

    if (t == 0) {
        float s = 0.f;
        #pragma unroll
        for (int i = 0; i < 16; ++i) s += vred[i];
        __hip_atomic_store(&bpart[blockIdx.x], s, __ATOMIC_RELEASE,
                           __HIP_MEMORY_SCOPE_AGENT);
        unsigned old = __hip_atomic_fetch_add(cnt, 1u, __ATOMIC_ACQ_REL,
                                              __HIP_MEMORY_SCOPE_AGENT);
        last_flag = (old == NPART - 1) ? 1u : 0u;
    }
    __syncthreads();

    if (last_flag) {   // block-uniform
        fr[t] = __hip_atomic_load(&bpart[t], __ATOMIC_ACQUIRE,
                                  __HIP_MEMORY_SCOPE_AGENT);
        __syncthreads();
        for (int s2 = 128; s2 > 0; s2 >>= 1) {
            if (t < s2) fr[t] += fr[t + s2];
            __syncthreads();
        }
        if (t == 0) out[0] = fr[0] * (1.0f / 67108864.0f);  // / 8192^2
    }
}

extern "C" void kernel_launch(void* const* d_in, const int* in_sizes, int n_in,
                              void* d_out, int out_size, void* d_ws, size_t ws_size,
                              hipStream_t stream)
{
    const float* p1 = (const float*)d_in[0];
    const float* p2 = (const float*)d_in[1];
    float* ws       = (float*)d_ws;
    float* partials = ws;                                  // 256*12288
    float* bpart    = ws + (long)NPART * PART_STRIDE;      // 256
    unsigned* cnt   = (unsigned*)(ws + 3146240);           // 1

    fused_gram_kernel<<<NPART, 1024, 0, stream>>>(p1, p2, partials, cnt);
    reduce_kernel   <<<NPART, 256, 0, stream>>>(partials, bpart, cnt, (float*)d_out);
}